// Round 18
// baseline (133.795 us; speedup 1.0000x reference)
//
#include <hip/hip_runtime.h>

#define T_SEQ 512
#define EMB 32
#define HID 128
#define BB 2          // batch rows per block -> 256 blocks, 1 block/CU
#define LDSW 160      // h row stride in bf16 elems
#define TCH 128       // x timesteps per LDS chunk (4 chunks total)

typedef __attribute__((ext_vector_type(8))) short short8;   // 8 bf16
typedef __attribute__((ext_vector_type(4))) short short4v;  // 4 bf16
typedef __attribute__((ext_vector_type(4))) float f32x4;

__device__ __forceinline__ short f2bf(float f) {
  union { float f; unsigned u; } v; v.f = f;
  unsigned r = (v.u + 0x7FFFu + ((v.u >> 16) & 1u)) >> 16;  // RNE
  return (short)r;
}

__device__ __forceinline__ float tanh_fast(float a) {
  float e = __expf(2.0f * a);
  return 1.0f - 2.0f * __builtin_amdgcn_rcpf(e + 1.0f);
}

#define MFMA(a, b, c) __builtin_amdgcn_mfma_f32_16x16x32_bf16((a), (b), (c), 0, 0, 0)

// R17 structure (LDS-staged x, zero in-loop vmem loads, p-pipelined off-chain)
// with the h-MFMA dependency flattened to DEPTH 1: four independent MFMAs per
// n-tile (c1 carries p as C), summed by a 2-level add tree in the tail.
// Chain: barrier -> 4 ds_read -> 1 MFMA dep -> add tree -> tanh -> ds_write.
__global__ __launch_bounds__(256) void rnn_fused_kernel(
    const float* __restrict__ x, const float* __restrict__ Wx,
    const float* __restrict__ Wh, const float* __restrict__ bh,
    float* __restrict__ out) {
  __shared__ short hbuf[2][BB][LDSW];          // 1280 B
  __shared__ short xlds[TCH][BB][EMB];         // 16 KB: [t&127][row][e]

  const int tid = threadIdx.x;
  const int wid = tid >> 6;        // wave 0..3, owns cols [32w, 32w+32)
  const int lane = tid & 63;
  const int l4 = lane >> 4, lm = lane & 15;
  const int row0 = blockIdx.x * BB;
  const int colbase = wid * 32;

  for (int i = tid; i < 2 * BB * LDSW; i += 256) ((short*)hbuf)[i] = 0;

  // ---- weights into registers (B-frag: col = lane&15, k = 8*(lane>>4)+j) ----
  short8 whf[2][4]; short8 wxf[2]; float bv[2];
#pragma unroll
  for (int nt = 0; nt < 2; ++nt) {
    const int col = colbase + 16 * nt + lm;
    bv[nt] = bh[col];
#pragma unroll
    for (int kb = 0; kb < 4; ++kb) {
      short8 f;
#pragma unroll
      for (int j = 0; j < 8; ++j)
        f[j] = f2bf(Wh[(size_t)(32 * kb + 8 * l4 + j) * HID + col]);
      whf[nt][kb] = f;
    }
    short8 fx;
#pragma unroll
    for (int j = 0; j < 8; ++j)
      fx[j] = f2bf(Wx[(size_t)(8 * l4 + j) * HID + col]);
    wxf[nt] = fx;
  }

  const int rsel = l4 & 1;         // batch row parity this lane outputs
  const int csel = l4 >> 1;        // which 16-col tile
  const int ocol = colbase + 16 * csel + lm;

  const unsigned out_off0 =
      ((unsigned)(row0 + rsel) * T_SEQ) * (HID * 4) + (unsigned)ocol * 4;
  float* outb = out;
  float* hfinp = out + (size_t)512 * T_SEQ * HID + (size_t)(row0 + rsel) * HID + ocol;

  // LDS ptrs: h A-frag read row = lm&1 (k-offset 8*l4 folded); x A-frag read
  // row = lm&1, elems 8*l4..+7 (8 distinct 16B lines across 128 B: conflict-free)
  const short* hr0 = &hbuf[0][lm & 1][8 * l4];
  const short* hr1 = &hbuf[1][lm & 1][8 * l4];
  short* hw0 = &hbuf[0][rsel][ocol];
  short* hw1 = &hbuf[1][rsel][ocol];
  const short* xbase = &xlds[0][lm & 1][8 * l4];

  const float* xsrc = x + (size_t)row0 * T_SEQ * EMB;  // 2 contiguous rows

  const f32x4 z_  = {0.f, 0.f, 0.f, 0.f};
  const f32x4 cb0 = {bv[0], bv[0], bv[0], bv[0]};   // bias as x-MFMA C
  const f32x4 cb1 = {bv[1], bv[1], bv[1], bv[1]};

  f32x4 pA0, pA1, pB0, pB1;   // pipelined x-projection (even/odd step regs)
  float th_last = 0.f;

  // ---- stage chunk [TB, TB+TCH) of x into LDS as bf16 ----
#define STAGE(TB) do {                                                           \
    _Pragma("unroll")                                                            \
    for (int k = 0; k < (BB * TCH * EMB / 4) / 256; ++k) { /* 8 f32x4/thread */  \
      const int flat4 = tid + k * 256;                                           \
      const int e4 = flat4 & 7;                                                  \
      const int tt = (flat4 >> 3) & (TCH - 1);                                   \
      const int r  = flat4 >> 10;                                                \
      const f32x4 v4 = *(const f32x4*)(xsrc + (size_t)r * T_SEQ * EMB +          \
                                       (size_t)((TB) + tt) * EMB + e4 * 4);      \
      short4v s4;                                                                \
      s4[0] = f2bf(v4[0]); s4[1] = f2bf(v4[1]);                                  \
      s4[2] = f2bf(v4[2]); s4[3] = f2bf(v4[3]);                                  \
      *(short4v*)&xlds[tt][r][e4 * 4] = s4;                                      \
    }                                                                            \
  } while (0)

  // p(T) = x(T)@Wx + bias  (standalone, used at chunk starts)
#define PCOMP(T, P0, P1) do {                                                    \
    short8 xn = *(const short8*)(xbase + ((T) & (TCH - 1)) * (BB * EMB));        \
    P0 = MFMA(xn, wxf[0], cb0);                                                  \
    P1 = MFMA(xn, wxf[1], cb1);                                                  \
  } while (0)

  // One recurrence step, depth-1 h-MFMA chains. PNEXT=1: compute p(T+1) in
  // the dep shadow (no consumer until after the next barrier).
#define RSTEP(T, PAR, PNEXT, PIN0, PIN1, POUT0, POUT1) do {                      \
    const short* hb_ = (PAR) ? hr0 : hr1;   /* prev = PAR^1 */                   \
    short8 ah0 = *(const short8*)(hb_ + 0);                                      \
    short8 ah1 = *(const short8*)(hb_ + 32);                                     \
    short8 ah2 = *(const short8*)(hb_ + 64);                                     \
    short8 ah3 = *(const short8*)(hb_ + 96);                                     \
    f32x4 c10 = MFMA(ah0, whf[0][0], PIN0);  /* p(T) enters as C */              \
    f32x4 c11 = MFMA(ah0, whf[1][0], PIN1);                                      \
    f32x4 c20 = MFMA(ah1, whf[0][1], z_);                                        \
    f32x4 c21 = MFMA(ah1, whf[1][1], z_);                                        \
    f32x4 c30 = MFMA(ah2, whf[0][2], z_);                                        \
    f32x4 c31 = MFMA(ah2, whf[1][2], z_);                                        \
    f32x4 c40 = MFMA(ah3, whf[0][3], z_);                                        \
    f32x4 c41 = MFMA(ah3, whf[1][3], z_);                                        \
    if (PNEXT) {                             /* off-chain: p(T+1) */             \
      short8 xn = *(const short8*)(xbase + (((T) + 1) & (TCH - 1)) * (BB * EMB));\
      POUT0 = MFMA(xn, wxf[0], cb0);                                             \
      POUT1 = MFMA(xn, wxf[1], cb1);                                             \
    }                                                                            \
    float e10 = rsel ? c10[1] : c10[0];                                          \
    float e20 = rsel ? c20[1] : c20[0];                                          \
    float e30 = rsel ? c30[1] : c30[0];                                          \
    float e40 = rsel ? c40[1] : c40[0];                                          \
    float e11 = rsel ? c11[1] : c11[0];                                          \
    float e21 = rsel ? c21[1] : c21[0];                                          \
    float e31 = rsel ? c31[1] : c31[0];                                          \
    float e41 = rsel ? c41[1] : c41[0];                                          \
    float v0 = (e10 + e20) + (e30 + e40);                                        \
    float v1 = (e11 + e21) + (e31 + e41);                                        \
    float v_ = csel ? v1 : v0;                                                   \
    float th_ = tanh_fast(v_);                                                   \
    *((PAR) ? hw1 : hw0) = f2bf(th_);   /* cur = PAR; 1 ds_write_b16 */          \
    asm volatile("global_store_dword %0, %1, %2"                                 \
                 :: "v"(out_off0 + (unsigned)(T) * 512u), "v"(th_), "s"(outb));  \
    th_last = th_;                                                               \
    asm volatile("s_waitcnt lgkmcnt(0)\n\ts_barrier" ::: "memory");              \
  } while (0)

  STAGE(0);
  __syncthreads();      // chunk 0 + hbuf init visible
  PCOMP(0, pA0, pA1);

  for (int tb = 0; tb < T_SEQ; tb += TCH) {
#pragma unroll 4
    for (int t = tb; t < tb + TCH - 2; t += 2) {
      RSTEP(t + 0, 0, 1, pA0, pA1, pB0, pB1);
      RSTEP(t + 1, 1, 1, pB0, pB1, pA0, pA1);
    }
    RSTEP(tb + TCH - 2, 0, 1, pA0, pA1, pB0, pB1);
    RSTEP(tb + TCH - 1, 1, 0, pB0, pB1, pA0, pA1);  // last of chunk: no p-next
    if (tb + TCH < T_SEQ) {
      STAGE(tb + TCH);    // xlds reads all done (previous RSTEP barrier)
      __syncthreads();
      PCOMP(tb + TCH, pA0, pA1);
    }
  }
#undef RSTEP
#undef PCOMP
#undef STAGE

  *hfinp = th_last;  // final h (t = T-1), off the loop
}

extern "C" void kernel_launch(void* const* d_in, const int* in_sizes, int n_in,
                              void* d_out, int out_size, void* d_ws, size_t ws_size,
                              hipStream_t stream) {
  const float* x  = (const float*)d_in[0];
  const float* Wx = (const float*)d_in[1];
  const float* Wh = (const float*)d_in[2];
  const float* bh = (const float*)d_in[3];
  float* out = (float*)d_out;
  (void)in_sizes; (void)n_in; (void)out_size; (void)d_ws; (void)ws_size;
  rnn_fused_kernel<<<512 / BB, 256, 0, stream>>>(x, Wx, Wh, bh, out);
}

// Round 19
// 116.811 us; speedup vs baseline: 1.1454x; 1.1454x over previous
//
#include <hip/hip_runtime.h>

#define T_SEQ 512
#define EMB 32
#define HID 128
#define BB 2          // batch rows per block -> 256 blocks, 1 block/CU
#define LDSW 160      // h row stride in bf16 elems
#define TCH 128       // x timesteps per LDS chunk (4 chunks total)

typedef __attribute__((ext_vector_type(8))) short short8;   // 8 bf16
typedef __attribute__((ext_vector_type(4))) short short4v;  // 4 bf16
typedef __attribute__((ext_vector_type(4))) float f32x4;

__device__ __forceinline__ short f2bf(float f) {
  union { float f; unsigned u; } v; v.f = f;
  unsigned r = (v.u + 0x7FFFu + ((v.u >> 16) & 1u)) >> 16;  // RNE
  return (short)r;
}

__device__ __forceinline__ float tanh_fast(float a) {
  float e = __expf(2.0f * a);
  return 1.0f - 2.0f * __builtin_amdgcn_rcpf(e + 1.0f);
}

#define MFMA(a, b, c) __builtin_amdgcn_mfma_f32_16x16x32_bf16((a), (b), (c), 0, 0, 0)

// R17 (best verified: 116.9 us): LDS-staged x, zero in-loop vmem loads,
// p-pipelined off-chain, depth-2 h-MFMA chains. R18's depth-1 variant
// regressed (tail waits on all 8 MFMAs + 8-way extract) - reverted.
__global__ __launch_bounds__(256) void rnn_fused_kernel(
    const float* __restrict__ x, const float* __restrict__ Wx,
    const float* __restrict__ Wh, const float* __restrict__ bh,
    float* __restrict__ out) {
  __shared__ short hbuf[2][BB][LDSW];          // 1280 B
  __shared__ short xlds[TCH][BB][EMB];         // 16 KB: [t&127][row][e]

  const int tid = threadIdx.x;
  const int wid = tid >> 6;        // wave 0..3, owns cols [32w, 32w+32)
  const int lane = tid & 63;
  const int l4 = lane >> 4, lm = lane & 15;
  const int row0 = blockIdx.x * BB;
  const int colbase = wid * 32;

  for (int i = tid; i < 2 * BB * LDSW; i += 256) ((short*)hbuf)[i] = 0;

  // ---- weights into registers (B-frag: col = lane&15, k = 8*(lane>>4)+j) ----
  short8 whf[2][4]; short8 wxf[2]; float bv[2];
#pragma unroll
  for (int nt = 0; nt < 2; ++nt) {
    const int col = colbase + 16 * nt + lm;
    bv[nt] = bh[col];
#pragma unroll
    for (int kb = 0; kb < 4; ++kb) {
      short8 f;
#pragma unroll
      for (int j = 0; j < 8; ++j)
        f[j] = f2bf(Wh[(size_t)(32 * kb + 8 * l4 + j) * HID + col]);
      whf[nt][kb] = f;
    }
    short8 fx;
#pragma unroll
    for (int j = 0; j < 8; ++j)
      fx[j] = f2bf(Wx[(size_t)(8 * l4 + j) * HID + col]);
    wxf[nt] = fx;
  }

  const int rsel = l4 & 1;         // batch row parity this lane outputs
  const int csel = l4 >> 1;        // which 16-col tile
  const int ocol = colbase + 16 * csel + lm;

  const unsigned out_off0 =
      ((unsigned)(row0 + rsel) * T_SEQ) * (HID * 4) + (unsigned)ocol * 4;
  float* outb = out;
  float* hfinp = out + (size_t)512 * T_SEQ * HID + (size_t)(row0 + rsel) * HID + ocol;

  // LDS ptrs: h A-frag read row = lm&1 (k-offset 8*l4 folded); x A-frag read
  // row = lm&1, elems 8*l4..+7 (8 distinct 16B lines across 128 B: conflict-free)
  const short* hr0 = &hbuf[0][lm & 1][8 * l4];
  const short* hr1 = &hbuf[1][lm & 1][8 * l4];
  short* hw0 = &hbuf[0][rsel][ocol];
  short* hw1 = &hbuf[1][rsel][ocol];
  const short* xbase = &xlds[0][lm & 1][8 * l4];

  const float* xsrc = x + (size_t)row0 * T_SEQ * EMB;  // 2 contiguous rows

  const f32x4 z_  = {0.f, 0.f, 0.f, 0.f};
  const f32x4 cb0 = {bv[0], bv[0], bv[0], bv[0]};   // bias as x-MFMA C
  const f32x4 cb1 = {bv[1], bv[1], bv[1], bv[1]};

  f32x4 pA0, pA1, pB0, pB1;   // pipelined x-projection (even/odd step regs)
  float th_last = 0.f;

  // ---- stage chunk [TB, TB+TCH) of x into LDS as bf16 ----
#define STAGE(TB) do {                                                           \
    _Pragma("unroll")                                                            \
    for (int k = 0; k < (BB * TCH * EMB / 4) / 256; ++k) { /* 8 f32x4/thread */  \
      const int flat4 = tid + k * 256;                                           \
      const int e4 = flat4 & 7;                                                  \
      const int tt = (flat4 >> 3) & (TCH - 1);                                   \
      const int r  = flat4 >> 10;                                                \
      const f32x4 v4 = *(const f32x4*)(xsrc + (size_t)r * T_SEQ * EMB +          \
                                       (size_t)((TB) + tt) * EMB + e4 * 4);      \
      short4v s4;                                                                \
      s4[0] = f2bf(v4[0]); s4[1] = f2bf(v4[1]);                                  \
      s4[2] = f2bf(v4[2]); s4[3] = f2bf(v4[3]);                                  \
      *(short4v*)&xlds[tt][r][e4 * 4] = s4;                                      \
    }                                                                            \
  } while (0)

  // p(T) = x(T)@Wx + bias  (standalone, used at chunk starts)
#define PCOMP(T, P0, P1) do {                                                    \
    short8 xn = *(const short8*)(xbase + ((T) & (TCH - 1)) * (BB * EMB));        \
    P0 = MFMA(xn, wxf[0], cb0);                                                  \
    P1 = MFMA(xn, wxf[1], cb1);                                                  \
  } while (0)

  // One recurrence step. PNEXT=1: also compute p(T+1) in the dep shadow.
#define RSTEP(T, PAR, PNEXT, PIN0, PIN1, POUT0, POUT1) do {                      \
    const short* hb_ = (PAR) ? hr0 : hr1;   /* prev = PAR^1 */                   \
    short8 ah0 = *(const short8*)(hb_ + 0);                                      \
    short8 ah1 = *(const short8*)(hb_ + 32);                                     \
    short8 ah2 = *(const short8*)(hb_ + 64);                                     \
    short8 ah3 = *(const short8*)(hb_ + 96);                                     \
    f32x4 a0 = MFMA(ah0, whf[0][0], PIN0);   /* p(T) enters as C */              \
    f32x4 a1 = MFMA(ah0, whf[1][0], PIN1);                                       \
    f32x4 b0 = MFMA(ah2, whf[0][2], z_);                                         \
    f32x4 b1 = MFMA(ah2, whf[1][2], z_);                                         \
    a0 = MFMA(ah1, whf[0][1], a0);                                               \
    a1 = MFMA(ah1, whf[1][1], a1);                                               \
    b0 = MFMA(ah3, whf[0][3], b0);                                               \
    b1 = MFMA(ah3, whf[1][3], b1);                                               \
    if (PNEXT) {                             /* off-chain: p(T+1) */             \
      short8 xn = *(const short8*)(xbase + (((T) + 1) & (TCH - 1)) * (BB * EMB));\
      POUT0 = MFMA(xn, wxf[0], cb0);                                             \
      POUT1 = MFMA(xn, wxf[1], cb1);                                             \
    }                                                                            \
    float vA0 = rsel ? a0[1] : a0[0];                                            \
    float vB0 = rsel ? b0[1] : b0[0];                                            \
    float vA1 = rsel ? a1[1] : a1[0];                                            \
    float vB1 = rsel ? b1[1] : b1[0];                                            \
    float v_ = csel ? (vA1 + vB1) : (vA0 + vB0);                                 \
    float th_ = tanh_fast(v_);                                                   \
    *((PAR) ? hw1 : hw0) = f2bf(th_);   /* cur = PAR; 1 ds_write_b16 */          \
    asm volatile("global_store_dword %0, %1, %2"                                 \
                 :: "v"(out_off0 + (unsigned)(T) * 512u), "v"(th_), "s"(outb));  \
    th_last = th_;                                                               \
    asm volatile("s_waitcnt lgkmcnt(0)\n\ts_barrier" ::: "memory");              \
  } while (0)

  STAGE(0);
  __syncthreads();      // chunk 0 + hbuf init visible
  PCOMP(0, pA0, pA1);

  for (int tb = 0; tb < T_SEQ; tb += TCH) {
#pragma unroll 4
    for (int t = tb; t < tb + TCH - 2; t += 2) {
      RSTEP(t + 0, 0, 1, pA0, pA1, pB0, pB1);
      RSTEP(t + 1, 1, 1, pB0, pB1, pA0, pA1);
    }
    RSTEP(tb + TCH - 2, 0, 1, pA0, pA1, pB0, pB1);
    RSTEP(tb + TCH - 1, 1, 0, pB0, pB1, pA0, pA1);  // last of chunk: no p-next
    if (tb + TCH < T_SEQ) {
      STAGE(tb + TCH);    // xlds reads all done (previous RSTEP barrier)
      __syncthreads();
      PCOMP(tb + TCH, pA0, pA1);
    }
  }
#undef RSTEP
#undef PCOMP
#undef STAGE

  *hfinp = th_last;  // final h (t = T-1), off the loop
}

extern "C" void kernel_launch(void* const* d_in, const int* in_sizes, int n_in,
                              void* d_out, int out_size, void* d_ws, size_t ws_size,
                              hipStream_t stream) {
  const float* x  = (const float*)d_in[0];
  const float* Wx = (const float*)d_in[1];
  const float* Wh = (const float*)d_in[2];
  const float* bh = (const float*)d_in[3];
  float* out = (float*)d_out;
  (void)in_sizes; (void)n_in; (void)out_size; (void)d_ws; (void)ws_size;
  rnn_fused_kernel<<<512 / BB, 256, 0, stream>>>(x, Wx, Wh, bh, out);
}

// Round 20
// 113.808 us; speedup vs baseline: 1.1756x; 1.0264x over previous
//
#include <hip/hip_runtime.h>

#define T_SEQ 512
#define EMB 32
#define HID 128
#define BB 2          // batch rows per block -> 256 blocks, 1 block/CU
#define LDSW 160      // h row stride in bf16 elems
#define TCH 128       // x timesteps per LDS chunk (4 chunks total)

typedef __attribute__((ext_vector_type(8))) short short8;   // 8 bf16
typedef __attribute__((ext_vector_type(4))) short short4v;  // 4 bf16
typedef __attribute__((ext_vector_type(4))) float f32x4;

__device__ __forceinline__ short f2bf(float f) {
  union { float f; unsigned u; } v; v.f = f;
  unsigned r = (v.u + 0x7FFFu + ((v.u >> 16) & 1u)) >> 16;  // RNE
  return (short)r;
}

__device__ __forceinline__ float tanh_fast(float a) {
  float e = __expf(2.0f * a);
  return 1.0f - 2.0f * __builtin_amdgcn_rcpf(e + 1.0f);
}

#define MFMA(a, b, c) __builtin_amdgcn_mfma_f32_16x16x32_bf16((a), (b), (c), 0, 0, 0)

// R17 structure (116.9/116.8 us verified twice) + async staging split:
// chunk k+1's 8 global loads issue right after step 2 of chunk k (pinned by
// RSTEP "memory" clobbers), so only convert+ds_write remain at the boundary.
// Serial chain unchanged: barrier -> 4 ds_read -> depth-2 MFMA (p as C of
// first a-MFMA) -> 2-way tail -> tanh -> ds_write; p(t+1) in the dep shadow.
__global__ __launch_bounds__(256) void rnn_fused_kernel(
    const float* __restrict__ x, const float* __restrict__ Wx,
    const float* __restrict__ Wh, const float* __restrict__ bh,
    float* __restrict__ out) {
  __shared__ short hbuf[2][BB][LDSW];          // 1280 B
  __shared__ short xlds[TCH][BB][EMB];         // 16 KB: [t&127][row][e]

  const int tid = threadIdx.x;
  const int wid = tid >> 6;        // wave 0..3, owns cols [32w, 32w+32)
  const int lane = tid & 63;
  const int l4 = lane >> 4, lm = lane & 15;
  const int row0 = blockIdx.x * BB;
  const int colbase = wid * 32;

  for (int i = tid; i < 2 * BB * LDSW; i += 256) ((short*)hbuf)[i] = 0;

  // ---- weights into registers (B-frag: col = lane&15, k = 8*(lane>>4)+j) ----
  short8 whf[2][4]; short8 wxf[2]; float bv[2];
#pragma unroll
  for (int nt = 0; nt < 2; ++nt) {
    const int col = colbase + 16 * nt + lm;
    bv[nt] = bh[col];
#pragma unroll
    for (int kb = 0; kb < 4; ++kb) {
      short8 f;
#pragma unroll
      for (int j = 0; j < 8; ++j)
        f[j] = f2bf(Wh[(size_t)(32 * kb + 8 * l4 + j) * HID + col]);
      whf[nt][kb] = f;
    }
    short8 fx;
#pragma unroll
    for (int j = 0; j < 8; ++j)
      fx[j] = f2bf(Wx[(size_t)(8 * l4 + j) * HID + col]);
    wxf[nt] = fx;
  }

  const int rsel = l4 & 1;         // batch row parity this lane outputs
  const int csel = l4 >> 1;        // which 16-col tile
  const int ocol = colbase + 16 * csel + lm;

  const unsigned out_off0 =
      ((unsigned)(row0 + rsel) * T_SEQ) * (HID * 4) + (unsigned)ocol * 4;
  float* outb = out;
  float* hfinp = out + (size_t)512 * T_SEQ * HID + (size_t)(row0 + rsel) * HID + ocol;

  // LDS ptrs: h A-frag read row = lm&1 (k-offset 8*l4 folded); x A-frag read
  // row = lm&1, elems 8*l4..+7 (8 distinct 16B lines across 128 B: conflict-free)
  const short* hr0 = &hbuf[0][lm & 1][8 * l4];
  const short* hr1 = &hbuf[1][lm & 1][8 * l4];
  short* hw0 = &hbuf[0][rsel][ocol];
  short* hw1 = &hbuf[1][rsel][ocol];
  const short* xbase = &xlds[0][lm & 1][8 * l4];

  const float* xsrc = x + (size_t)row0 * T_SEQ * EMB;  // 2 contiguous rows

  const f32x4 z_  = {0.f, 0.f, 0.f, 0.f};
  const f32x4 cb0 = {bv[0], bv[0], bv[0], bv[0]};   // bias as x-MFMA C
  const f32x4 cb1 = {bv[1], bv[1], bv[1], bv[1]};

  f32x4 pA0, pA1, pB0, pB1;   // pipelined x-projection (even/odd step regs)
  f32x4 xstage[8];            // staged next-chunk x (static-indexed, 32 VGPR)
  float th_last = 0.f;

  // ---- issue chunk [TB, TB+TCH) global loads into registers ----
#define STAGE_LOAD(TB) do {                                                      \
    _Pragma("unroll")                                                            \
    for (int k = 0; k < 8; ++k) {          /* 8 f32x4 / thread */                \
      const int flat4 = tid + k * 256;                                           \
      const int e4 = flat4 & 7;                                                  \
      const int tt = (flat4 >> 3) & (TCH - 1);                                   \
      const int r  = flat4 >> 10;                                                \
      xstage[k] = *(const f32x4*)(xsrc + (size_t)r * T_SEQ * EMB +               \
                                  (size_t)((TB) + tt) * EMB + e4 * 4);           \
    }                                                                            \
  } while (0)

  // ---- convert + write staged chunk into LDS ----
#define STAGE_WRITE() do {                                                       \
    _Pragma("unroll")                                                            \
    for (int k = 0; k < 8; ++k) {                                                \
      const int flat4 = tid + k * 256;                                           \
      const int e4 = flat4 & 7;                                                  \
      const int tt = (flat4 >> 3) & (TCH - 1);                                   \
      const int r  = flat4 >> 10;                                                \
      short4v s4;                                                                \
      s4[0] = f2bf(xstage[k][0]); s4[1] = f2bf(xstage[k][1]);                    \
      s4[2] = f2bf(xstage[k][2]); s4[3] = f2bf(xstage[k][3]);                    \
      *(short4v*)&xlds[tt][r][e4 * 4] = s4;                                      \
    }                                                                            \
  } while (0)

  // p(T) = x(T)@Wx + bias  (standalone, used at chunk starts)
#define PCOMP(T, P0, P1) do {                                                    \
    short8 xn = *(const short8*)(xbase + ((T) & (TCH - 1)) * (BB * EMB));        \
    P0 = MFMA(xn, wxf[0], cb0);                                                  \
    P1 = MFMA(xn, wxf[1], cb1);                                                  \
  } while (0)

  // One recurrence step. PNEXT=1: also compute p(T+1) in the dep shadow.
#define RSTEP(T, PAR, PNEXT, PIN0, PIN1, POUT0, POUT1) do {                      \
    const short* hb_ = (PAR) ? hr0 : hr1;   /* prev = PAR^1 */                   \
    short8 ah0 = *(const short8*)(hb_ + 0);                                      \
    short8 ah1 = *(const short8*)(hb_ + 32);                                     \
    short8 ah2 = *(const short8*)(hb_ + 64);                                     \
    short8 ah3 = *(const short8*)(hb_ + 96);                                     \
    f32x4 a0 = MFMA(ah0, whf[0][0], PIN0);   /* p(T) enters as C */              \
    f32x4 a1 = MFMA(ah0, whf[1][0], PIN1);                                       \
    f32x4 b0 = MFMA(ah2, whf[0][2], z_);                                         \
    f32x4 b1 = MFMA(ah2, whf[1][2], z_);                                         \
    a0 = MFMA(ah1, whf[0][1], a0);                                               \
    a1 = MFMA(ah1, whf[1][1], a1);                                               \
    b0 = MFMA(ah3, whf[0][3], b0);                                               \
    b1 = MFMA(ah3, whf[1][3], b1);                                               \
    if (PNEXT) {                             /* off-chain: p(T+1) */             \
      short8 xn = *(const short8*)(xbase + (((T) + 1) & (TCH - 1)) * (BB * EMB));\
      POUT0 = MFMA(xn, wxf[0], cb0);                                             \
      POUT1 = MFMA(xn, wxf[1], cb1);                                             \
    }                                                                            \
    float vA0 = rsel ? a0[1] : a0[0];                                            \
    float vB0 = rsel ? b0[1] : b0[0];                                            \
    float vA1 = rsel ? a1[1] : a1[0];                                            \
    float vB1 = rsel ? b1[1] : b1[0];                                            \
    float v_ = csel ? (vA1 + vB1) : (vA0 + vB0);                                 \
    float th_ = tanh_fast(v_);                                                   \
    *((PAR) ? hw1 : hw0) = f2bf(th_);   /* cur = PAR; 1 ds_write_b16 */          \
    asm volatile("global_store_dword %0, %1, %2"                                 \
                 :: "v"(out_off0 + (unsigned)(T) * 512u), "v"(th_), "s"(outb));  \
    th_last = th_;                                                               \
    asm volatile("s_waitcnt lgkmcnt(0)\n\ts_barrier" ::: "memory");              \
  } while (0)

  STAGE_LOAD(0);
  STAGE_WRITE();
  __syncthreads();      // chunk 0 + hbuf init visible
  PCOMP(0, pA0, pA1);

  for (int tb = 0; tb < T_SEQ; tb += TCH) {
    RSTEP(tb + 0, 0, 1, pA0, pA1, pB0, pB1);
    RSTEP(tb + 1, 1, 1, pB0, pB1, pA0, pA1);
    if (tb + TCH < T_SEQ) STAGE_LOAD(tb + TCH);   // issue early, ~126 steps of cover
#pragma unroll 4
    for (int t = tb + 2; t < tb + TCH - 2; t += 2) {
      RSTEP(t + 0, 0, 1, pA0, pA1, pB0, pB1);
      RSTEP(t + 1, 1, 1, pB0, pB1, pA0, pA1);
    }
    RSTEP(tb + TCH - 2, 0, 1, pA0, pA1, pB0, pB1);
    RSTEP(tb + TCH - 1, 1, 0, pB0, pB1, pA0, pA1);  // last of chunk: no p-next
    if (tb + TCH < T_SEQ) {
      STAGE_WRITE();      // loads long since landed; xlds reads done (barrier)
      __syncthreads();
      PCOMP(tb + TCH, pA0, pA1);
    }
  }
#undef RSTEP
#undef PCOMP
#undef STAGE_WRITE
#undef STAGE_LOAD

  *hfinp = th_last;  // final h (t = T-1), off the loop
}

extern "C" void kernel_launch(void* const* d_in, const int* in_sizes, int n_in,
                              void* d_out, int out_size, void* d_ws, size_t ws_size,
                              hipStream_t stream) {
  const float* x  = (const float*)d_in[0];
  const float* Wx = (const float*)d_in[1];
  const float* Wh = (const float*)d_in[2];
  const float* bh = (const float*)d_in[3];
  float* out = (float*)d_out;
  (void)in_sizes; (void)n_in; (void)out_size; (void)d_ws; (void)ws_size;
  rnn_fused_kernel<<<512 / BB, 256, 0, stream>>>(x, Wx, Wh, bh, out);
}

// Round 21
// 112.598 us; speedup vs baseline: 1.1882x; 1.0107x over previous
//
#include <hip/hip_runtime.h>

#define T_SEQ 512
#define EMB 32
#define HID 128
#define BB 2          // batch rows per block -> 256 blocks, 1 block/CU
#define LDSW 160      // h row stride in bf16 elems
#define TCH 128       // x timesteps per LDS chunk (4 chunks total)

typedef __attribute__((ext_vector_type(8))) short short8;   // 8 bf16
typedef __attribute__((ext_vector_type(4))) short short4v;  // 4 bf16
typedef __attribute__((ext_vector_type(4))) float f32x4;

__device__ __forceinline__ short f2bf(float f) {
  union { float f; unsigned u; } v; v.f = f;
  unsigned r = (v.u + 0x7FFFu + ((v.u >> 16) & 1u)) >> 16;  // RNE
  return (short)r;
}

__device__ __forceinline__ float tanh_fast(float a) {
  float e = __expf(2.0f * a);
  return 1.0f - 2.0f * __builtin_amdgcn_rcpf(e + 1.0f);
}

#define MFMA(a, b, c) __builtin_amdgcn_mfma_f32_16x16x32_bf16((a), (b), (c), 0, 0, 0)

// R20 structure (113.8 us verified) with ONE change: the on-chain h->bf16
// conversion (tanh -> LDS write) uses v_cvt_pk_bf16_f32 (1 instr) instead of
// the 3-op manual RNE. R7's indictment of cvt_pk was a misattribution (R8
// proved the A-row remap was the sole bug); this round is the clean A/B.
__global__ __launch_bounds__(256) void rnn_fused_kernel(
    const float* __restrict__ x, const float* __restrict__ Wx,
    const float* __restrict__ Wh, const float* __restrict__ bh,
    float* __restrict__ out) {
  __shared__ short hbuf[2][BB][LDSW];          // 1280 B
  __shared__ short xlds[TCH][BB][EMB];         // 16 KB: [t&127][row][e]

  const int tid = threadIdx.x;
  const int wid = tid >> 6;        // wave 0..3, owns cols [32w, 32w+32)
  const int lane = tid & 63;
  const int l4 = lane >> 4, lm = lane & 15;
  const int row0 = blockIdx.x * BB;
  const int colbase = wid * 32;

  for (int i = tid; i < 2 * BB * LDSW; i += 256) ((short*)hbuf)[i] = 0;

  // ---- weights into registers (B-frag: col = lane&15, k = 8*(lane>>4)+j) ----
  short8 whf[2][4]; short8 wxf[2]; float bv[2];
#pragma unroll
  for (int nt = 0; nt < 2; ++nt) {
    const int col = colbase + 16 * nt + lm;
    bv[nt] = bh[col];
#pragma unroll
    for (int kb = 0; kb < 4; ++kb) {
      short8 f;
#pragma unroll
      for (int j = 0; j < 8; ++j)
        f[j] = f2bf(Wh[(size_t)(32 * kb + 8 * l4 + j) * HID + col]);
      whf[nt][kb] = f;
    }
    short8 fx;
#pragma unroll
    for (int j = 0; j < 8; ++j)
      fx[j] = f2bf(Wx[(size_t)(8 * l4 + j) * HID + col]);
    wxf[nt] = fx;
  }

  const int rsel = l4 & 1;         // batch row parity this lane outputs
  const int csel = l4 >> 1;        // which 16-col tile
  const int ocol = colbase + 16 * csel + lm;

  const unsigned out_off0 =
      ((unsigned)(row0 + rsel) * T_SEQ) * (HID * 4) + (unsigned)ocol * 4;
  float* outb = out;
  float* hfinp = out + (size_t)512 * T_SEQ * HID + (size_t)(row0 + rsel) * HID + ocol;

  // LDS ptrs: h A-frag read row = lm&1 (k-offset 8*l4 folded); x A-frag read
  // row = lm&1, elems 8*l4..+7 (8 distinct 16B lines across 128 B: conflict-free)
  const short* hr0 = &hbuf[0][lm & 1][8 * l4];
  const short* hr1 = &hbuf[1][lm & 1][8 * l4];
  short* hw0 = &hbuf[0][rsel][ocol];
  short* hw1 = &hbuf[1][rsel][ocol];
  const short* xbase = &xlds[0][lm & 1][8 * l4];

  const float* xsrc = x + (size_t)row0 * T_SEQ * EMB;  // 2 contiguous rows

  const f32x4 z_  = {0.f, 0.f, 0.f, 0.f};
  const f32x4 cb0 = {bv[0], bv[0], bv[0], bv[0]};   // bias as x-MFMA C
  const f32x4 cb1 = {bv[1], bv[1], bv[1], bv[1]};

  f32x4 pA0, pA1, pB0, pB1;   // pipelined x-projection (even/odd step regs)
  f32x4 xstage[8];            // staged next-chunk x (static-indexed, 32 VGPR)
  float th_last = 0.f;

  // ---- issue chunk [TB, TB+TCH) global loads into registers ----
#define STAGE_LOAD(TB) do {                                                      \
    _Pragma("unroll")                                                            \
    for (int k = 0; k < 8; ++k) {          /* 8 f32x4 / thread */                \
      const int flat4 = tid + k * 256;                                           \
      const int e4 = flat4 & 7;                                                  \
      const int tt = (flat4 >> 3) & (TCH - 1);                                   \
      const int r  = flat4 >> 10;                                                \
      xstage[k] = *(const f32x4*)(xsrc + (size_t)r * T_SEQ * EMB +               \
                                  (size_t)((TB) + tt) * EMB + e4 * 4);           \
    }                                                                            \
  } while (0)

  // ---- convert + write staged chunk into LDS ----
#define STAGE_WRITE() do {                                                       \
    _Pragma("unroll")                                                            \
    for (int k = 0; k < 8; ++k) {                                                \
      const int flat4 = tid + k * 256;                                           \
      const int e4 = flat4 & 7;                                                  \
      const int tt = (flat4 >> 3) & (TCH - 1);                                   \
      const int r  = flat4 >> 10;                                                \
      short4v s4;                                                                \
      s4[0] = f2bf(xstage[k][0]); s4[1] = f2bf(xstage[k][1]);                    \
      s4[2] = f2bf(xstage[k][2]); s4[3] = f2bf(xstage[k][3]);                    \
      *(short4v*)&xlds[tt][r][e4 * 4] = s4;                                      \
    }                                                                            \
  } while (0)

  // p(T) = x(T)@Wx + bias  (standalone, used at chunk starts)
#define PCOMP(T, P0, P1) do {                                                    \
    short8 xn = *(const short8*)(xbase + ((T) & (TCH - 1)) * (BB * EMB));        \
    P0 = MFMA(xn, wxf[0], cb0);                                                  \
    P1 = MFMA(xn, wxf[1], cb1);                                                  \
  } while (0)

  // One recurrence step. PNEXT=1: also compute p(T+1) in the dep shadow.
#define RSTEP(T, PAR, PNEXT, PIN0, PIN1, POUT0, POUT1) do {                      \
    const short* hb_ = (PAR) ? hr0 : hr1;   /* prev = PAR^1 */                   \
    short8 ah0 = *(const short8*)(hb_ + 0);                                      \
    short8 ah1 = *(const short8*)(hb_ + 32);                                     \
    short8 ah2 = *(const short8*)(hb_ + 64);                                     \
    short8 ah3 = *(const short8*)(hb_ + 96);                                     \
    f32x4 a0 = MFMA(ah0, whf[0][0], PIN0);   /* p(T) enters as C */              \
    f32x4 a1 = MFMA(ah0, whf[1][0], PIN1);                                       \
    f32x4 b0 = MFMA(ah2, whf[0][2], z_);                                         \
    f32x4 b1 = MFMA(ah2, whf[1][2], z_);                                         \
    a0 = MFMA(ah1, whf[0][1], a0);                                               \
    a1 = MFMA(ah1, whf[1][1], a1);                                               \
    b0 = MFMA(ah3, whf[0][3], b0);                                               \
    b1 = MFMA(ah3, whf[1][3], b1);                                               \
    if (PNEXT) {                             /* off-chain: p(T+1) */             \
      short8 xn = *(const short8*)(xbase + (((T) + 1) & (TCH - 1)) * (BB * EMB));\
      POUT0 = MFMA(xn, wxf[0], cb0);                                             \
      POUT1 = MFMA(xn, wxf[1], cb1);                                             \
    }                                                                            \
    float vA0 = rsel ? a0[1] : a0[0];                                            \
    float vB0 = rsel ? b0[1] : b0[0];                                            \
    float vA1 = rsel ? a1[1] : a1[0];                                            \
    float vB1 = rsel ? b1[1] : b1[0];                                            \
    float v_ = csel ? (vA1 + vB1) : (vA0 + vB0);                                 \
    float th_ = tanh_fast(v_);                                                   \
    unsigned us_;                                                                \
    asm("v_cvt_pk_bf16_f32 %0, %1, %1" : "=v"(us_) : "v"(th_));                  \
    *((PAR) ? hw1 : hw0) = (short)us_;   /* cur = PAR; 1 ds_write_b16 */         \
    asm volatile("global_store_dword %0, %1, %2"                                 \
                 :: "v"(out_off0 + (unsigned)(T) * 512u), "v"(th_), "s"(outb));  \
    th_last = th_;                                                               \
    asm volatile("s_waitcnt lgkmcnt(0)\n\ts_barrier" ::: "memory");              \
  } while (0)

  STAGE_LOAD(0);
  STAGE_WRITE();
  __syncthreads();      // chunk 0 + hbuf init visible
  PCOMP(0, pA0, pA1);

  for (int tb = 0; tb < T_SEQ; tb += TCH) {
    RSTEP(tb + 0, 0, 1, pA0, pA1, pB0, pB1);
    RSTEP(tb + 1, 1, 1, pB0, pB1, pA0, pA1);
    if (tb + TCH < T_SEQ) STAGE_LOAD(tb + TCH);   // issue early, ~126 steps of cover
#pragma unroll 4
    for (int t = tb + 2; t < tb + TCH - 2; t += 2) {
      RSTEP(t + 0, 0, 1, pA0, pA1, pB0, pB1);
      RSTEP(t + 1, 1, 1, pB0, pB1, pA0, pA1);
    }
    RSTEP(tb + TCH - 2, 0, 1, pA0, pA1, pB0, pB1);
    RSTEP(tb + TCH - 1, 1, 0, pB0, pB1, pA0, pA1);  // last of chunk: no p-next
    if (tb + TCH < T_SEQ) {
      STAGE_WRITE();      // loads long since landed; xlds reads done (barrier)
      __syncthreads();
      PCOMP(tb + TCH, pA0, pA1);
    }
  }
#undef RSTEP
#undef PCOMP
#undef STAGE_WRITE
#undef STAGE_LOAD

  *hfinp = th_last;  // final h (t = T-1), off the loop
}

extern "C" void kernel_launch(void* const* d_in, const int* in_sizes, int n_in,
                              void* d_out, int out_size, void* d_ws, size_t ws_size,
                              hipStream_t stream) {
  const float* x  = (const float*)d_in[0];
  const float* Wx = (const float*)d_in[1];
  const float* Wh = (const float*)d_in[2];
  const float* bh = (const float*)d_in[3];
  float* out = (float*)d_out;
  (void)in_sizes; (void)n_in; (void)out_size; (void)d_ws; (void)ws_size;
  rnn_fused_kernel<<<512 / BB, 256, 0, stream>>>(x, Wx, Wh, bh, out);
}